// Round 8
// baseline (246.723 us; speedup 1.0000x reference)
//
#include <hip/hip_runtime.h>
#include <stdint.h>

#define B_   2
#define N_   16384
#define S_   4096
#define D2_  256
#define CIN_ 397
#define KP_  416      // Cin padded to 13*32 for MFMA K-slabs
#define C_   128
#define OC_  13
#define NCHUNK_ 16
#define CHS_ (S_ / NCHUNK_)       // 256 points per scan chunk
#define NCAND_ (NCHUNK_ * 3)      // 48 candidates per query
#define XBI_P 296                 // xbi LDS pitch in u16
#define TP_  16                   // mega tile: 16 points/block

typedef unsigned short u16;
typedef unsigned int u32;
typedef short s16x8 __attribute__((ext_vector_type(8)));
typedef float f32x4 __attribute__((ext_vector_type(4)));

#define MFMA16(a, b, c) __builtin_amdgcn_mfma_f32_16x16x32_bf16((a), (b), (c), 0, 0, 0)

__device__ __forceinline__ float b2f(u16 h) {
  union { unsigned int u; float f; } v; v.u = ((unsigned int)h) << 16; return v.f;
}
__device__ __forceinline__ u16 f2b(float f) {
  union { float f; unsigned int u; } v; v.f = f;
  unsigned int r = v.u + 0x7fffu + ((v.u >> 16) & 1u);
  return (u16)(r >> 16);
}

// ---------------------------------------------------------------------------
// setup_scan: ONE launch. Blocks [0,2048): knn scan (dispatched first --
// exactly 8/CU, saturates). [2048,3072): transpose points1 -> npT.
// [3072,3584): transpose points2 -> p2t. [3584,3648): weight prep + BN fold.
// ---------------------------------------------------------------------------
__device__ __forceinline__ void transpose_body(
    const float* __restrict__ in, u16* __restrict__ out,
    int C, int S, int opitch, int b, int s0, int c0,
    float* __restrict__ tile, int tr, int tc4) {
  const float* ip = in + (size_t)b * C * S;
  u16* op = out + (size_t)b * S * opitch;
#pragma unroll
  for (int r = 0; r < 64; r += 16) {
    float4 v = *(const float4*)(ip + (size_t)(c0 + tr + r) * S + s0 + tc4);
    tile[(tr + r) * 65 + tc4 + 0] = v.x;
    tile[(tr + r) * 65 + tc4 + 1] = v.y;
    tile[(tr + r) * 65 + tc4 + 2] = v.z;
    tile[(tr + r) * 65 + tc4 + 3] = v.w;
  }
  __syncthreads();
#pragma unroll
  for (int r = 0; r < 64; r += 16) {
    ushort4 v;
    v.x = f2b(tile[(tc4 + 0) * 65 + tr + r]);
    v.y = f2b(tile[(tc4 + 1) * 65 + tr + r]);
    v.z = f2b(tile[(tc4 + 2) * 65 + tr + r]);
    v.w = f2b(tile[(tc4 + 3) * 65 + tr + r]);
    *(ushort4*)(op + (size_t)(s0 + tr + r) * opitch + c0 + tc4) = v;
  }
}

__global__ __launch_bounds__(256) void setup_scan_kernel(
    const float* __restrict__ xyz1, const float* __restrict__ xyz2,
    const float* __restrict__ points1, const float* __restrict__ points2,
    const float* __restrict__ fW, const float* __restrict__ fb,
    const float* __restrict__ fbn,
    const float* __restrict__ e1W, const float* __restrict__ e1b,
    const float* __restrict__ e1bn,
    const float* __restrict__ e2W, const float* __restrict__ e2b,
    const float* __restrict__ e2bn,
    const float* __restrict__ p1W, const float* __restrict__ p1b,
    const float* __restrict__ p1bn,
    const float* __restrict__ p2W, const float* __restrict__ p2b,
    const float* __restrict__ p2bn,
    u16* __restrict__ cand, u16* __restrict__ npT, u16* __restrict__ p2t,
    u16* __restrict__ Wf, u16* __restrict__ W1o,
    u16* __restrict__ W2o, u16* __restrict__ W3o,
    u16* __restrict__ Wp2, float* __restrict__ st) {
  __shared__ __align__(16) float smem[64 * 65];
  int id = blockIdx.x;
  int tid = threadIdx.x;

  if (id < 2048) {
    // ---- knn scan: branchless f32 candidate scan, top-3/chunk ----
    float4* pts = (float4*)smem;
    int chunk = id & 15;
    int ny = (id >> 4) & 63;
    int b = id >> 10;
    int s0 = chunk * CHS_;
    const float* x2 = xyz2 + ((size_t)b * S_ + s0) * 3;
    {
      float xx = x2[tid * 3], yy = x2[tid * 3 + 1], zz = x2[tid * 3 + 2];
      pts[tid] = make_float4(xx, yy, zz, fmaf(xx, xx, fmaf(yy, yy, zz * zz)));
    }
    __syncthreads();
    int n = ny * 256 + tid;
    const float* x1 = xyz1 + ((size_t)b * N_ + n) * 3;
    float ax = x1[0], ay = x1[1], az = x1[2];
    float n1 = fmaf(ax, ax, fmaf(ay, ay, az * az));
    u32 k0 = 0xFFFFFFFFu, k1 = 0xFFFFFFFFu, k2 = 0xFFFFFFFFu;
#pragma unroll 8
    for (int s = 0; s < CHS_; ++s) {
      float4 p = pts[s];
      float dot = fmaf(ax, p.x, fmaf(ay, p.y, az * p.z));
      float d = fmaf(-2.f, dot, n1 + p.w);
      d = fmaxf(d, 0.f);
      u32 key = (__float_as_uint(d) & 0xFFFFFF00u) | (u32)s;
      u32 nk0 = min(k0, key);
      u32 nk1 = min(k1, max(k0, key));
      u32 nk2 = min(k2, max(k1, key));
      k0 = nk0; k1 = nk1; k2 = nk2;
    }
    u16* co = cand + ((size_t)(b * N_ + n)) * NCAND_ + chunk * 3;
    co[0] = (u16)((k0 & 0xFFu) + s0);
    co[1] = (u16)((k1 & 0xFFu) + s0);
    co[2] = (u16)((k2 & 0xFFu) + s0);
    return;
  }

  int tr = tid >> 4;
  int tc4 = (tid & 15) * 4;
  if (id < 3072) {
    int id2 = id - 2048;
    int sx = id2 & 255, sy = (id2 >> 8) & 1, b = id2 >> 9;
    transpose_body(points1, npT, 128, N_, 128, b, sx * 64, sy * 64, smem, tr, tc4);
    return;
  }
  if (id < 3584) {
    int id2 = id - 3072;
    int sx = id2 & 63, sy = (id2 >> 6) & 3, b = id2 >> 8;
    transpose_body(points2, p2t, 256, S_, 256, b, sx * 64, sy * 64, smem, tr, tc4);
    return;
  }
  // ---- weight prep ----
  int t = (id - 3584) * 256 + tid;
  int stride = 64 * 256;
  for (int i = t; i < 128 * KP_; i += stride) {
    int m = i / KP_, k = i - m * KP_;
    Wf[i] = (k < CIN_) ? f2b(fW[m * CIN_ + k]) : (u16)0;
  }
  for (int i = t; i < 128 * 128; i += stride) {
    W1o[i] = f2b(e1W[i]);
    W2o[i] = f2b(e2W[i]);
    W3o[i] = f2b(p1W[i]);
  }
  for (int i = t; i < 16 * 128; i += stride) {
    int m = i >> 7;
    Wp2[i] = (m < OC_) ? f2b(p2W[i]) : (u16)0;
  }
  for (int i = t; i < 5 * 128; i += stride) {
    int sg = i >> 7, c = i & 127;
    const float* bn; const float* bc; int Cc = 128;
    switch (sg) {
      case 0: bn = fbn;  bc = fb;  break;
      case 1: bn = e1bn; bc = e1b; break;
      case 2: bn = e2bn; bc = e2b; break;
      case 3: bn = p1bn; bc = p1b; break;
      default: bn = p2bn; bc = p2b; Cc = OC_; break;
    }
    float s = 0.f, tt = 0.f;
    if (c < Cc) {
      float g  = bn[0 * Cc + c], be = bn[1 * Cc + c];
      float mu = bn[2 * Cc + c], vv = bn[3 * Cc + c];
      float inv = 1.0f / sqrtf(vv + 1e-5f);
      s = g * inv;
      tt = (bc[c] - mu) * s + be;
    }
    st[sg * 256 + c] = s;
    st[sg * 256 + 128 + c] = tt;
  }
}

// ---------------------------------------------------------------------------
// f64 lexicographic (d, idx) top-3 insert -- matches stable top_k semantics
// ---------------------------------------------------------------------------
__device__ __forceinline__ void ins3(double d, int i,
                                     double& D0, double& D1, double& D2,
                                     int& I0, int& I1, int& I2) {
  if ((d < D2) || (d == D2 && i < I2)) {
    if ((d < D1) || (d == D1 && i < I1)) {
      D2 = D1; I2 = I1;
      if ((d < D0) || (d == D0 && i < I0)) { D1 = D0; I1 = I0; D0 = d; I0 = i; }
      else                                  { D1 = d; I1 = i; }
    } else { D2 = d; I2 = i; }
  }
}

// ---------------------------------------------------------------------------
// mega: 16-point tile, 2048 blocks = 8 blocks/CU (32 waves/CU, wave-capped).
// [f64 tree-merge of 48 cands] + [interp prologue] + fuse -> ext1 ->
// ext2(+res) -> pred1 -> pred2. LDS ~18.6 KB; merge scratch aliases pool.
// MFMA 16x16x32 bf16; A[m=lane&15][k=(lane>>4)*8+j]; D col=lane&15, row=q*4+r
// ---------------------------------------------------------------------------
__device__ __forceinline__ void gemm16(const u16* __restrict__ W, const u16* xb,
                                       int l15, int lq, int wv, f32x4 acc[2]) {
  acc[0] = (f32x4){0.f, 0.f, 0.f, 0.f};
  acc[1] = (f32x4){0.f, 0.f, 0.f, 0.f};
#pragma unroll
  for (int ks = 0; ks < 4; ++ks) {
    int ko = ks * 32 + lq * 8;
    s16x8 b0 = *(const s16x8*)(xb + l15 * 136 + ko);
#pragma unroll
    for (int mtl = 0; mtl < 2; ++mtl) {
      s16x8 a = *(const s16x8*)(W + (size_t)((wv * 2 + mtl) * 16 + l15) * 128 + ko);
      acc[mtl] = MFMA16(a, b0, acc[mtl]);
    }
  }
}

__global__ __launch_bounds__(256, 8) void mega_kernel(
    const float* __restrict__ xyz1, const float* __restrict__ xyz2,
    const u16* __restrict__ cand,
    const u16* __restrict__ npT, const u16* __restrict__ p2t,
    const float* __restrict__ last_pred,
    const u16* __restrict__ Wf,
    const u16* __restrict__ W1, const u16* __restrict__ W2,
    const u16* __restrict__ W3, const u16* __restrict__ Wp2,
    const float* __restrict__ st, float* __restrict__ out) {
  // pool: xb0 [0,2176) u16 | xb1 [2176,4352) | xbi [4352,9088)
  // phase0 aliases: md (768 f64 @ byte 0) | mi (768 i32 @ byte 6144)
  __shared__ __align__(16) u16 pool[9088];
  __shared__ float wL[TP_][3];
  __shared__ int   iL[TP_][3];
  u16* xb0 = pool;
  u16* xb1 = pool + 2176;
  u16* xbi = pool + 4352;
  double* md = (double*)pool;
  int*    mi = (int*)(pool + 3072);

  int b = blockIdx.y;
  int n0 = blockIdx.x * TP_;
  int tid = threadIdx.x;
  int wv = tid >> 6, lane = tid & 63;
  int l15 = lane & 15, lq = lane >> 4;
  f32x4 acc[2];

  // ---- phase 0a: f64 partial top-3 (16 parts/query, 3 cands each) ----
  int qi = tid >> 4, part = tid & 15;
  double D0 = 1e300, D1 = 1e300, D2v = 1e300;
  int I0 = 2147483647, I1 = 2147483647, I2 = 2147483647;
  {
#pragma clang fp contract(off)
    int qg = b * N_ + n0 + qi;
    const u16* ci = cand + (size_t)qg * NCAND_ + part * 3;
    const float* x1 = xyz1 + (size_t)qg * 3;
    double ax = x1[0], ay = x1[1], az = x1[2];
    double n1 = (ax * ax + ay * ay) + az * az;
    const float* x2b = xyz2 + (size_t)b * S_ * 3;
#pragma unroll
    for (int j = 0; j < 3; ++j) {
      int i = ci[j];
      const float* p = x2b + (size_t)i * 3;
      double px = p[0], py = p[1], pz = p[2];
      double n2 = (px * px + py * py) + pz * pz;
      double dot = (ax * px + ay * py) + az * pz;
      double d = (n1 + n2) - 2.0 * dot;
      ins3(d, i, D0, D1, D2v, I0, I1, I2);
    }
    int po = (qi * 16 + part) * 3;
    md[po + 0] = D0; mi[po + 0] = I0;
    md[po + 1] = D1; mi[po + 1] = I1;
    md[po + 2] = D2v; mi[po + 2] = I2;
  }
  __syncthreads();

  // ---- phase 0b: log-tree merge of sorted triples (exact total order) ----
#pragma unroll
  for (int step = 8; step >= 1; step >>= 1) {
    if (part < step) {
      int pp = (qi * 16 + part + step) * 3;
      double e0 = md[pp], e1 = md[pp + 1], e2 = md[pp + 2];
      int j0 = mi[pp], j1 = mi[pp + 1], j2 = mi[pp + 2];
      ins3(e0, j0, D0, D1, D2v, I0, I1, I2);
      ins3(e1, j1, D0, D1, D2v, I0, I1, I2);
      ins3(e2, j2, D0, D1, D2v, I0, I1, I2);
      int po = (qi * 16 + part) * 3;
      md[po + 0] = D0; mi[po + 0] = I0;
      md[po + 1] = D1; mi[po + 1] = I1;
      md[po + 2] = D2v; mi[po + 2] = I2;
    }
    __syncthreads();
  }
  if (part == 0) {
#pragma clang fp contract(off)
    double r0 = 1.0 / (D0 + 1e-8);
    double r1 = 1.0 / (D1 + 1e-8);
    double r2 = 1.0 / (D2v + 1e-8);
    double sum = (r0 + r1) + r2;
    wL[qi][0] = (float)(r0 / sum);
    wL[qi][1] = (float)(r1 / sum);
    wL[qi][2] = (float)(r2 / sum);
    iL[qi][0] = I0; iL[qi][1] = I1; iL[qi][2] = I2;
  }
  __syncthreads();

  // ---- prologue: wave wv gathers+interpolates points [4wv, 4wv+4) ----
  {
    const float* lpb = last_pred + (size_t)b * S_ * OC_;
    const u16* p2b = p2t + (size_t)b * S_ * D2_;
#pragma unroll 2
    for (int i = 0; i < 4; ++i) {
      int p = wv * 4 + i;
      float w0 = wL[p][0], w1 = wL[p][1], w2 = wL[p][2];
      int i0 = iL[p][0], i1 = iL[p][1], i2 = iL[p][2];
      ushort4 a0 = *(const ushort4*)(p2b + (size_t)i0 * D2_ + lane * 4);
      ushort4 a1 = *(const ushort4*)(p2b + (size_t)i1 * D2_ + lane * 4);
      ushort4 a2 = *(const ushort4*)(p2b + (size_t)i2 * D2_ + lane * 4);
      ushort4 v;
      v.x = f2b((w0 * b2f(a0.x) + w1 * b2f(a1.x)) + w2 * b2f(a2.x));
      v.y = f2b((w0 * b2f(a0.y) + w1 * b2f(a1.y)) + w2 * b2f(a2.y));
      v.z = f2b((w0 * b2f(a0.z) + w1 * b2f(a1.z)) + w2 * b2f(a2.z));
      v.w = f2b((w0 * b2f(a0.w) + w1 * b2f(a1.w)) + w2 * b2f(a2.w));
      *(ushort4*)(&xbi[p * XBI_P + lane * 4]) = v;
      if (lane < 32) {
        u16 pv = 0;
        if (lane < OC_) {
          pv = f2b((w0 * lpb[i0 * OC_ + lane] + w1 * lpb[i1 * OC_ + lane])
                   + w2 * lpb[i2 * OC_ + lane]);
        }
        xbi[p * XBI_P + 256 + lane] = pv;   // cols 256..287 (k=384..415)
      }
    }
  }
  __syncthreads();

  // ---- stage 1: fuse (K=416): k<128 from npT (global), k>=128 from xbi ----
  acc[0] = (f32x4){0.f, 0.f, 0.f, 0.f};
  acc[1] = (f32x4){0.f, 0.f, 0.f, 0.f};
  {
    const u16* brow0 = npT + ((size_t)(b * N_ + n0 + l15)) * 128;
#pragma unroll 1
    for (int ks = 0; ks < 4; ++ks) {
      int ko = ks * 32 + lq * 8;
      s16x8 bf0 = *(const s16x8*)(brow0 + ko);
#pragma unroll
      for (int mtl = 0; mtl < 2; ++mtl) {
        s16x8 a = *(const s16x8*)(Wf + (size_t)((wv * 2 + mtl) * 16 + l15) * KP_ + ko);
        acc[mtl] = MFMA16(a, bf0, acc[mtl]);
      }
    }
#pragma unroll 1
    for (int ks = 0; ks < 9; ++ks) {
      int kk = ks * 32 + lq * 8;
      s16x8 bf0 = *(const s16x8*)(&xbi[l15 * XBI_P + kk]);
#pragma unroll
      for (int mtl = 0; mtl < 2; ++mtl) {
        s16x8 a = *(const s16x8*)(Wf + (size_t)((wv * 2 + mtl) * 16 + l15) * KP_ + 128 + kk);
        acc[mtl] = MFMA16(a, bf0, acc[mtl]);
      }
    }
  }
#pragma unroll
  for (int mtl = 0; mtl < 2; ++mtl) {
    int m4 = (wv * 2 + mtl) * 16 + lq * 4;
    f32x4 sc = *(const f32x4*)(st + 0 * 256 + m4);
    f32x4 bi = *(const f32x4*)(st + 0 * 256 + 128 + m4);
    ushort4 v;
    v.x = f2b(fmaxf(acc[mtl][0] * sc[0] + bi[0], 0.f));
    v.y = f2b(fmaxf(acc[mtl][1] * sc[1] + bi[1], 0.f));
    v.z = f2b(fmaxf(acc[mtl][2] * sc[2] + bi[2], 0.f));
    v.w = f2b(fmaxf(acc[mtl][3] * sc[3] + bi[3], 0.f));
    *(ushort4*)(&xb0[l15 * 136 + m4]) = v;
  }
  __syncthreads();

  // ---- stage 2: ext1 (K=128), xb0 -> xb1 ----
  gemm16(W1, xb0, l15, lq, wv, acc);
#pragma unroll
  for (int mtl = 0; mtl < 2; ++mtl) {
    int m4 = (wv * 2 + mtl) * 16 + lq * 4;
    f32x4 sc = *(const f32x4*)(st + 1 * 256 + m4);
    f32x4 bi = *(const f32x4*)(st + 1 * 256 + 128 + m4);
    ushort4 v;
    v.x = f2b(fmaxf(acc[mtl][0] * sc[0] + bi[0], 0.f));
    v.y = f2b(fmaxf(acc[mtl][1] * sc[1] + bi[1], 0.f));
    v.z = f2b(fmaxf(acc[mtl][2] * sc[2] + bi[2], 0.f));
    v.w = f2b(fmaxf(acc[mtl][3] * sc[3] + bi[3], 0.f));
    *(ushort4*)(&xb1[l15 * 136 + m4]) = v;
  }
  __syncthreads();

  // ---- stage 3: ext2 (K=128), xb1 -> xb0, + residual(xb0), store out0 ----
  gemm16(W2, xb1, l15, lq, wv, acc);
#pragma unroll
  for (int mtl = 0; mtl < 2; ++mtl) {
    int m4 = (wv * 2 + mtl) * 16 + lq * 4;
    f32x4 sc = *(const f32x4*)(st + 2 * 256 + m4);
    f32x4 bi = *(const f32x4*)(st + 2 * 256 + 128 + m4);
    int n_g = n0 + l15;
    ushort4 xp = *(const ushort4*)(&xb0[l15 * 136 + m4]);
    float v0 = fmaxf(acc[mtl][0] * sc[0] + bi[0] + b2f(xp.x), 0.f);
    float v1 = fmaxf(acc[mtl][1] * sc[1] + bi[1] + b2f(xp.y), 0.f);
    float v2 = fmaxf(acc[mtl][2] * sc[2] + bi[2] + b2f(xp.z), 0.f);
    float v3 = fmaxf(acc[mtl][3] * sc[3] + bi[3] + b2f(xp.w), 0.f);
    ushort4 v;
    v.x = f2b(v0); v.y = f2b(v1); v.z = f2b(v2); v.w = f2b(v3);
    *(ushort4*)(&xb0[l15 * 136 + m4]) = v;
    out[((size_t)(b * C_ + m4 + 0)) * N_ + n_g] = v0;
    out[((size_t)(b * C_ + m4 + 1)) * N_ + n_g] = v1;
    out[((size_t)(b * C_ + m4 + 2)) * N_ + n_g] = v2;
    out[((size_t)(b * C_ + m4 + 3)) * N_ + n_g] = v3;
  }
  __syncthreads();

  // ---- stage 4: pred1 (K=128), xb0 -> xb1, store out1 ([B][N][128]) ----
  gemm16(W3, xb0, l15, lq, wv, acc);
  {
    float* out1 = out + (size_t)B_ * C_ * N_;
#pragma unroll
    for (int mtl = 0; mtl < 2; ++mtl) {
      int m4 = (wv * 2 + mtl) * 16 + lq * 4;
      f32x4 sc = *(const f32x4*)(st + 3 * 256 + m4);
      f32x4 bi = *(const f32x4*)(st + 3 * 256 + 128 + m4);
      int n_g = n0 + l15;
      float v0 = fmaxf(acc[mtl][0] * sc[0] + bi[0], 0.f);
      float v1 = fmaxf(acc[mtl][1] * sc[1] + bi[1], 0.f);
      float v2 = fmaxf(acc[mtl][2] * sc[2] + bi[2], 0.f);
      float v3 = fmaxf(acc[mtl][3] * sc[3] + bi[3], 0.f);
      ushort4 v;
      v.x = f2b(v0); v.y = f2b(v1); v.z = f2b(v2); v.w = f2b(v3);
      *(ushort4*)(&xb1[l15 * 136 + m4]) = v;
      float4 o4 = make_float4(v0, v1, v2, v3);
      *(float4*)(out1 + ((size_t)(b * N_ + n_g)) * 128 + m4) = o4;
    }
  }
  __syncthreads();

  // ---- stage 5: pred2 (M=13 pad 16, K=128): wave 0 only ----
  if (wv == 0) {
    f32x4 a2 = (f32x4){0.f, 0.f, 0.f, 0.f};
#pragma unroll
    for (int ks = 0; ks < 4; ++ks) {
      int ko = ks * 32 + lq * 8;
      s16x8 b0 = *(const s16x8*)(&xb1[l15 * 136 + ko]);
      s16x8 a = *(const s16x8*)(Wp2 + (size_t)l15 * 128 + ko);
      a2 = MFMA16(a, b0, a2);
    }
    float* out2 = out + (size_t)B_ * C_ * N_ + (size_t)B_ * N_ * 128;
    f32x4 sc = *(const f32x4*)(st + 4 * 256 + lq * 4);
    f32x4 bi = *(const f32x4*)(st + 4 * 256 + 128 + lq * 4);
    int n_g = n0 + l15;
#pragma unroll
    for (int r = 0; r < 4; ++r) {
      int m = lq * 4 + r;
      if (m < OC_) {
        out2[((size_t)(b * N_ + n_g)) * OC_ + m] =
            fmaxf(a2[r] * sc[r] + bi[r], 0.f);
      }
    }
  }
}

// ---------------------------------------------------------------------------
extern "C" void kernel_launch(void* const* d_in, const int* in_sizes, int n_in,
                              void* d_out, int out_size, void* d_ws, size_t ws_size,
                              hipStream_t stream) {
  const float* xyz1      = (const float*)d_in[0];
  const float* xyz2      = (const float*)d_in[1];
  const float* points1   = (const float*)d_in[2];
  const float* points2   = (const float*)d_in[3];
  const float* last_pred = (const float*)d_in[4];
  const float* fuse_W    = (const float*)d_in[5];
  const float* fuse_b    = (const float*)d_in[6];
  const float* fuse_bn   = (const float*)d_in[7];
  const float* ext1_W    = (const float*)d_in[8];
  const float* ext1_b    = (const float*)d_in[9];
  const float* ext1_bn   = (const float*)d_in[10];
  const float* ext2_W    = (const float*)d_in[11];
  const float* ext2_b    = (const float*)d_in[12];
  const float* ext2_bn   = (const float*)d_in[13];
  const float* pred1_W   = (const float*)d_in[14];
  const float* pred1_b   = (const float*)d_in[15];
  const float* pred1_bn  = (const float*)d_in[16];
  const float* pred2_W   = (const float*)d_in[17];
  const float* pred2_b   = (const float*)d_in[18];
  const float* pred2_bn  = (const float*)d_in[19];

  char* ws = (char*)d_ws;
  u16*   npT  = (u16*)(ws + 0);                // 2*16384*128*2 =  8,388,608
  u16*   p2t  = (u16*)(ws + 8388608);          // 2*4096*256*2  =  4,194,304
  u16*   cand = (u16*)(ws + 12582912);         // 2*16384*48*2  =  3,145,728
  u16*   Wf   = (u16*)(ws + 15728640);         // 128*416*2     =    106,496
  u16*   W1   = (u16*)(ws + 15835136);         // 128*128*2     =     32,768
  u16*   W2   = (u16*)(ws + 15867904);         //                     32,768
  u16*   W3   = (u16*)(ws + 15900672);         //                     32,768
  u16*   Wp2  = (u16*)(ws + 15933440);         // 16*128*2      =      4,096
  float* st   = (float*)(ws + 15937536);       // 5*256*4       =      5,120

  setup_scan_kernel<<<dim3(3648), dim3(256), 0, stream>>>(
      xyz1, xyz2, points1, points2,
      fuse_W, fuse_b, fuse_bn, ext1_W, ext1_b, ext1_bn, ext2_W, ext2_b, ext2_bn,
      pred1_W, pred1_b, pred1_bn, pred2_W, pred2_b, pred2_bn,
      cand, npT, p2t, Wf, W1, W2, W3, Wp2, st);

  mega_kernel<<<dim3(N_ / TP_, B_), dim3(256), 0, stream>>>(
      xyz1, xyz2, cand, npT, p2t, last_pred,
      Wf, W1, W2, W3, Wp2, st, (float*)d_out);
}

// Round 9
// 205.492 us; speedup vs baseline: 1.2006x; 1.2006x over previous
//
#include <hip/hip_runtime.h>
#include <stdint.h>

#define B_   2
#define N_   16384
#define S_   4096
#define D2_  256
#define CIN_ 397
#define KP_  416      // Cin padded to 13*32 for MFMA K-slabs
#define C_   128
#define OC_  13
#define NCHUNK_ 16
#define CHS_ (S_ / NCHUNK_)       // 256 points per scan chunk
#define NCAND_ (NCHUNK_ * 3)      // 48 candidates per query
#define XBI_P 296                 // xbi LDS pitch in u16

typedef unsigned short u16;
typedef unsigned int u32;
typedef short s16x8 __attribute__((ext_vector_type(8)));
typedef float f32x4 __attribute__((ext_vector_type(4)));

#define MFMA16(a, b, c) __builtin_amdgcn_mfma_f32_16x16x32_bf16((a), (b), (c), 0, 0, 0)

__device__ __forceinline__ float b2f(u16 h) {
  union { unsigned int u; float f; } v; v.u = ((unsigned int)h) << 16; return v.f;
}
__device__ __forceinline__ u16 f2b(float f) {
  union { float f; unsigned int u; } v; v.f = f;
  unsigned int r = v.u + 0x7fffu + ((v.u >> 16) & 1u);
  return (u16)(r >> 16);
}

// ---------------------------------------------------------------------------
// setup_scan: ONE launch. Blocks [0,2048): knn scan. [2048,3072): transpose
// points1 -> npT. [3072,3584): transpose points2 -> p2t. [3584,3648): prep.
// ---------------------------------------------------------------------------
__device__ __forceinline__ void transpose_body(
    const float* __restrict__ in, u16* __restrict__ out,
    int C, int S, int opitch, int b, int s0, int c0,
    float* __restrict__ tile, int tr, int tc4) {
  const float* ip = in + (size_t)b * C * S;
  u16* op = out + (size_t)b * S * opitch;
#pragma unroll
  for (int r = 0; r < 64; r += 16) {
    float4 v = *(const float4*)(ip + (size_t)(c0 + tr + r) * S + s0 + tc4);
    tile[(tr + r) * 65 + tc4 + 0] = v.x;
    tile[(tr + r) * 65 + tc4 + 1] = v.y;
    tile[(tr + r) * 65 + tc4 + 2] = v.z;
    tile[(tr + r) * 65 + tc4 + 3] = v.w;
  }
  __syncthreads();
#pragma unroll
  for (int r = 0; r < 64; r += 16) {
    ushort4 v;
    v.x = f2b(tile[(tc4 + 0) * 65 + tr + r]);
    v.y = f2b(tile[(tc4 + 1) * 65 + tr + r]);
    v.z = f2b(tile[(tc4 + 2) * 65 + tr + r]);
    v.w = f2b(tile[(tc4 + 3) * 65 + tr + r]);
    *(ushort4*)(op + (size_t)(s0 + tr + r) * opitch + c0 + tc4) = v;
  }
}

__global__ __launch_bounds__(256) void setup_scan_kernel(
    const float* __restrict__ xyz1, const float* __restrict__ xyz2,
    const float* __restrict__ points1, const float* __restrict__ points2,
    const float* __restrict__ fW, const float* __restrict__ fb,
    const float* __restrict__ fbn,
    const float* __restrict__ e1W, const float* __restrict__ e1b,
    const float* __restrict__ e1bn,
    const float* __restrict__ e2W, const float* __restrict__ e2b,
    const float* __restrict__ e2bn,
    const float* __restrict__ p1W, const float* __restrict__ p1b,
    const float* __restrict__ p1bn,
    const float* __restrict__ p2W, const float* __restrict__ p2b,
    const float* __restrict__ p2bn,
    u16* __restrict__ cand, u16* __restrict__ npT, u16* __restrict__ p2t,
    u16* __restrict__ Wf, u16* __restrict__ W1o,
    u16* __restrict__ W2o, u16* __restrict__ W3o,
    u16* __restrict__ Wp2, float* __restrict__ st) {
  __shared__ __align__(16) float smem[64 * 65];
  int id = blockIdx.x;
  int tid = threadIdx.x;

  if (id < 2048) {
    float4* pts = (float4*)smem;
    int chunk = id & 15;
    int ny = (id >> 4) & 63;
    int b = id >> 10;
    int s0 = chunk * CHS_;
    const float* x2 = xyz2 + ((size_t)b * S_ + s0) * 3;
    {
      float xx = x2[tid * 3], yy = x2[tid * 3 + 1], zz = x2[tid * 3 + 2];
      pts[tid] = make_float4(xx, yy, zz, fmaf(xx, xx, fmaf(yy, yy, zz * zz)));
    }
    __syncthreads();
    int n = ny * 256 + tid;
    const float* x1 = xyz1 + ((size_t)b * N_ + n) * 3;
    float ax = x1[0], ay = x1[1], az = x1[2];
    float n1 = fmaf(ax, ax, fmaf(ay, ay, az * az));
    u32 k0 = 0xFFFFFFFFu, k1 = 0xFFFFFFFFu, k2 = 0xFFFFFFFFu;
#pragma unroll 8
    for (int s = 0; s < CHS_; ++s) {
      float4 p = pts[s];
      float dot = fmaf(ax, p.x, fmaf(ay, p.y, az * p.z));
      float d = fmaf(-2.f, dot, n1 + p.w);
      d = fmaxf(d, 0.f);
      u32 key = (__float_as_uint(d) & 0xFFFFFF00u) | (u32)s;
      u32 nk0 = min(k0, key);
      u32 nk1 = min(k1, max(k0, key));
      u32 nk2 = min(k2, max(k1, key));
      k0 = nk0; k1 = nk1; k2 = nk2;
    }
    u16* co = cand + ((size_t)(b * N_ + n)) * NCAND_ + chunk * 3;
    co[0] = (u16)((k0 & 0xFFu) + s0);
    co[1] = (u16)((k1 & 0xFFu) + s0);
    co[2] = (u16)((k2 & 0xFFu) + s0);
    return;
  }

  int tr = tid >> 4;
  int tc4 = (tid & 15) * 4;
  if (id < 3072) {
    int id2 = id - 2048;
    int sx = id2 & 255, sy = (id2 >> 8) & 1, b = id2 >> 9;
    transpose_body(points1, npT, 128, N_, 128, b, sx * 64, sy * 64, smem, tr, tc4);
    return;
  }
  if (id < 3584) {
    int id2 = id - 3072;
    int sx = id2 & 63, sy = (id2 >> 6) & 3, b = id2 >> 8;
    transpose_body(points2, p2t, 256, S_, 256, b, sx * 64, sy * 64, smem, tr, tc4);
    return;
  }
  int t = (id - 3584) * 256 + tid;
  int stride = 64 * 256;
  for (int i = t; i < 128 * KP_; i += stride) {
    int m = i / KP_, k = i - m * KP_;
    Wf[i] = (k < CIN_) ? f2b(fW[m * CIN_ + k]) : (u16)0;
  }
  for (int i = t; i < 128 * 128; i += stride) {
    W1o[i] = f2b(e1W[i]);
    W2o[i] = f2b(e2W[i]);
    W3o[i] = f2b(p1W[i]);
  }
  for (int i = t; i < 16 * 128; i += stride) {
    int m = i >> 7;
    Wp2[i] = (m < OC_) ? f2b(p2W[i]) : (u16)0;
  }
  for (int i = t; i < 5 * 128; i += stride) {
    int sg = i >> 7, c = i & 127;
    const float* bn; const float* bc; int Cc = 128;
    switch (sg) {
      case 0: bn = fbn;  bc = fb;  break;
      case 1: bn = e1bn; bc = e1b; break;
      case 2: bn = e2bn; bc = e2b; break;
      case 3: bn = p1bn; bc = p1b; break;
      default: bn = p2bn; bc = p2b; Cc = OC_; break;
    }
    float s = 0.f, tt = 0.f;
    if (c < Cc) {
      float g  = bn[0 * Cc + c], be = bn[1 * Cc + c];
      float mu = bn[2 * Cc + c], vv = bn[3 * Cc + c];
      float inv = 1.0f / sqrtf(vv + 1e-5f);
      s = g * inv;
      tt = (bc[c] - mu) * s + be;
    }
    st[sg * 256 + c] = s;
    st[sg * 256 + 128 + c] = tt;
  }
}

// ---------------------------------------------------------------------------
// f64 lexicographic (d, idx) top-3 insert -- matches stable top_k semantics
// ---------------------------------------------------------------------------
__device__ __forceinline__ void ins3(double d, int i,
                                     double& D0, double& D1, double& D2,
                                     int& I0, int& I1, int& I2) {
  if ((d < D2) || (d == D2 && i < I2)) {
    if ((d < D1) || (d == D1 && i < I1)) {
      D2 = D1; I2 = I1;
      if ((d < D0) || (d == D0 && i < I0)) { D1 = D0; I1 = I0; D0 = d; I0 = i; }
      else                                  { D1 = d; I1 = i; }
    } else { D2 = d; I2 = i; }
  }
}

// ---------------------------------------------------------------------------
// mega: 32-point tile, 1024 blocks, 4 blocks/CU (R7 structure) + software
// prefetch: npT B-rows at entry (hide under merge), next-stage A-weights
// issued during previous stage (barrier's vmcnt(0) drain retires them free).
// MFMA 16x16x32 bf16; A[m=lane&15][k=(lane>>4)*8+j]; D col=lane&15, row=q*4+r
// ---------------------------------------------------------------------------
__device__ __forceinline__ void gemm32_pre(const s16x8 wf[2][4], const u16* xb,
                                           int l15, int lq, f32x4 acc[2][2]) {
#pragma unroll
  for (int mtl = 0; mtl < 2; ++mtl) {
    acc[mtl][0] = (f32x4){0.f, 0.f, 0.f, 0.f};
    acc[mtl][1] = (f32x4){0.f, 0.f, 0.f, 0.f};
  }
#pragma unroll
  for (int ks = 0; ks < 4; ++ks) {
    int ko = ks * 32 + lq * 8;
    s16x8 b0 = *(const s16x8*)(xb + l15 * 136 + ko);
    s16x8 b1 = *(const s16x8*)(xb + (16 + l15) * 136 + ko);
#pragma unroll
    for (int mtl = 0; mtl < 2; ++mtl) {
      acc[mtl][0] = MFMA16(wf[mtl][ks], b0, acc[mtl][0]);
      acc[mtl][1] = MFMA16(wf[mtl][ks], b1, acc[mtl][1]);
    }
  }
}

__device__ __forceinline__ void loadWfrag(const u16* __restrict__ W,
                                          int l15, int lq, int wv, s16x8 wf[2][4]) {
#pragma unroll
  for (int mtl = 0; mtl < 2; ++mtl)
#pragma unroll
    for (int ks = 0; ks < 4; ++ks)
      wf[mtl][ks] = *(const s16x8*)(W + (size_t)((wv * 2 + mtl) * 16 + l15) * 128 +
                                    ks * 32 + lq * 8);
}

__global__ __launch_bounds__(256, 4) void mega_kernel(
    const float* __restrict__ xyz1, const float* __restrict__ xyz2,
    const u16* __restrict__ cand,
    const u16* __restrict__ npT, const u16* __restrict__ p2t,
    const float* __restrict__ last_pred,
    const u16* __restrict__ Wf,
    const u16* __restrict__ W1, const u16* __restrict__ W2,
    const u16* __restrict__ W3, const u16* __restrict__ Wp2,
    const float* __restrict__ st, float* __restrict__ out) {
  __shared__ __align__(16) u16 xb0[32 * 136];
  __shared__ __align__(16) u16 xb1[32 * 136];
  __shared__ u16 xbi[32 * XBI_P];
  __shared__ float wL[32][3];
  __shared__ int   iL[32][3];
  int b = blockIdx.y;
  int n0 = blockIdx.x * 32;
  int tid = threadIdx.x;
  int wv = tid >> 6, lane = tid & 63;
  int l15 = lane & 15, lq = lane >> 4;
  f32x4 acc[2][2];

  // ---- entry prefetch: npT B-rows for stage 1 (no dependencies) ----
  s16x8 npA[2][4];
  {
    const u16* brow0 = npT + ((size_t)(b * N_ + n0 + l15)) * 128;
    const u16* brow1 = brow0 + (size_t)16 * 128;
#pragma unroll
    for (int ks = 0; ks < 4; ++ks) {
      npA[0][ks] = *(const s16x8*)(brow0 + ks * 32 + lq * 8);
      npA[1][ks] = *(const s16x8*)(brow1 + ks * 32 + lq * 8);
    }
  }

  // ---- phase 0a: f64 partial top-3 (8 threads/query, 6 cands each) ----
  {
#pragma clang fp contract(off)
    double* md = (double*)xb0;   // [32][24]
    int*    mi = (int*)xb1;      // [32][24]
    int qi = tid >> 3, part = tid & 7;
    int qg = b * N_ + n0 + qi;
    const u16* ci = cand + (size_t)qg * NCAND_ + part * 6;
    const float* x1 = xyz1 + (size_t)qg * 3;
    double ax = x1[0], ay = x1[1], az = x1[2];
    double n1 = (ax * ax + ay * ay) + az * az;
    const float* x2b = xyz2 + (size_t)b * S_ * 3;
    double D0 = 1e300, D1 = 1e300, D2v = 1e300;
    int I0 = 2147483647, I1 = 2147483647, I2 = 2147483647;
#pragma unroll
    for (int j = 0; j < 6; ++j) {
      int i = ci[j];
      const float* p = x2b + (size_t)i * 3;
      double px = p[0], py = p[1], pz = p[2];
      double n2 = (px * px + py * py) + pz * pz;
      double dot = (ax * px + ay * py) + az * pz;
      double d = (n1 + n2) - 2.0 * dot;
      ins3(d, i, D0, D1, D2v, I0, I1, I2);
    }
    md[qi * 24 + part * 3 + 0] = D0; mi[qi * 24 + part * 3 + 0] = I0;
    md[qi * 24 + part * 3 + 1] = D1; mi[qi * 24 + part * 3 + 1] = I1;
    md[qi * 24 + part * 3 + 2] = D2v; mi[qi * 24 + part * 3 + 2] = I2;
  }
  __syncthreads();

  // ---- phase 0b: exact combine + weights (one thread per query) ----
  if (tid < 32) {
#pragma clang fp contract(off)
    double* md = (double*)xb0;
    int*    mi = (int*)xb1;
    double D0 = 1e300, D1 = 1e300, D2v = 1e300;
    int I0 = 2147483647, I1 = 2147483647, I2 = 2147483647;
    for (int j = 0; j < 24; ++j) {
      ins3(md[tid * 24 + j], mi[tid * 24 + j], D0, D1, D2v, I0, I1, I2);
    }
    double r0 = 1.0 / (D0 + 1e-8);
    double r1 = 1.0 / (D1 + 1e-8);
    double r2 = 1.0 / (D2v + 1e-8);
    double sum = (r0 + r1) + r2;
    wL[tid][0] = (float)(r0 / sum);
    wL[tid][1] = (float)(r1 / sum);
    wL[tid][2] = (float)(r2 / sum);
    iL[tid][0] = I0; iL[tid][1] = I1; iL[tid][2] = I2;
  }
  __syncthreads();

  // ---- prologue: wave wv gathers+interpolates points [8wv, 8wv+8) ----
  // fully unrolled: 24 gather loads in flight instead of ~6
  {
    const float* lpb = last_pred + (size_t)b * S_ * OC_;
    const u16* p2b = p2t + (size_t)b * S_ * D2_;
#pragma unroll
    for (int i = 0; i < 8; ++i) {
      int p = wv * 8 + i;
      float w0 = wL[p][0], w1 = wL[p][1], w2 = wL[p][2];
      int i0 = iL[p][0], i1 = iL[p][1], i2 = iL[p][2];
      ushort4 a0 = *(const ushort4*)(p2b + (size_t)i0 * D2_ + lane * 4);
      ushort4 a1 = *(const ushort4*)(p2b + (size_t)i1 * D2_ + lane * 4);
      ushort4 a2 = *(const ushort4*)(p2b + (size_t)i2 * D2_ + lane * 4);
      ushort4 v;
      v.x = f2b((w0 * b2f(a0.x) + w1 * b2f(a1.x)) + w2 * b2f(a2.x));
      v.y = f2b((w0 * b2f(a0.y) + w1 * b2f(a1.y)) + w2 * b2f(a2.y));
      v.z = f2b((w0 * b2f(a0.z) + w1 * b2f(a1.z)) + w2 * b2f(a2.z));
      v.w = f2b((w0 * b2f(a0.w) + w1 * b2f(a1.w)) + w2 * b2f(a2.w));
      *(ushort4*)(&xbi[p * XBI_P + lane * 4]) = v;
      if (lane < 32) {
        u16 pv = 0;
        if (lane < OC_) {
          pv = f2b((w0 * lpb[i0 * OC_ + lane] + w1 * lpb[i1 * OC_ + lane])
                   + w2 * lpb[i2 * OC_ + lane]);
        }
        xbi[p * XBI_P + 256 + lane] = pv;   // cols 256..287 (k=384..415)
      }
    }
  }
  __syncthreads();

  // ---- stage 1: fuse (K=416): prefetched npA + xbi; prefetch W1 ----
  s16x8 wnext[2][4];
  loadWfrag(W1, l15, lq, wv, wnext);   // in flight during fuse compute
#pragma unroll
  for (int mtl = 0; mtl < 2; ++mtl) {
    acc[mtl][0] = (f32x4){0.f, 0.f, 0.f, 0.f};
    acc[mtl][1] = (f32x4){0.f, 0.f, 0.f, 0.f};
  }
  {
#pragma unroll
    for (int ks = 0; ks < 4; ++ks) {
      int ko = ks * 32 + lq * 8;
      s16x8 bf0 = npA[0][ks];
      s16x8 bf1 = npA[1][ks];
#pragma unroll
      for (int mtl = 0; mtl < 2; ++mtl) {
        s16x8 a = *(const s16x8*)(Wf + (size_t)((wv * 2 + mtl) * 16 + l15) * KP_ + ko);
        acc[mtl][0] = MFMA16(a, bf0, acc[mtl][0]);
        acc[mtl][1] = MFMA16(a, bf1, acc[mtl][1]);
      }
    }
#pragma unroll 1
    for (int ks = 0; ks < 9; ++ks) {
      int kk = ks * 32 + lq * 8;
      s16x8 bf0 = *(const s16x8*)(&xbi[l15 * XBI_P + kk]);
      s16x8 bf1 = *(const s16x8*)(&xbi[(16 + l15) * XBI_P + kk]);
#pragma unroll
      for (int mtl = 0; mtl < 2; ++mtl) {
        s16x8 a = *(const s16x8*)(Wf + (size_t)((wv * 2 + mtl) * 16 + l15) * KP_ + 128 + kk);
        acc[mtl][0] = MFMA16(a, bf0, acc[mtl][0]);
        acc[mtl][1] = MFMA16(a, bf1, acc[mtl][1]);
      }
    }
  }
#pragma unroll
  for (int mtl = 0; mtl < 2; ++mtl) {
    int m4 = (wv * 2 + mtl) * 16 + lq * 4;
    f32x4 sc = *(const f32x4*)(st + 0 * 256 + m4);
    f32x4 bi = *(const f32x4*)(st + 0 * 256 + 128 + m4);
#pragma unroll
    for (int nt = 0; nt < 2; ++nt) {
      int n_l = nt * 16 + l15;
      ushort4 v;
      v.x = f2b(fmaxf(acc[mtl][nt][0] * sc[0] + bi[0], 0.f));
      v.y = f2b(fmaxf(acc[mtl][nt][1] * sc[1] + bi[1], 0.f));
      v.z = f2b(fmaxf(acc[mtl][nt][2] * sc[2] + bi[2], 0.f));
      v.w = f2b(fmaxf(acc[mtl][nt][3] * sc[3] + bi[3], 0.f));
      *(ushort4*)(&xb0[n_l * 136 + m4]) = v;
    }
  }
  __syncthreads();

  // ---- stage 2: ext1 (K=128), xb0 -> xb1; prefetch W2 ----
  s16x8 wcur[2][4];
#pragma unroll
  for (int mtl = 0; mtl < 2; ++mtl)
#pragma unroll
    for (int ks = 0; ks < 4; ++ks) wcur[mtl][ks] = wnext[mtl][ks];
  loadWfrag(W2, l15, lq, wv, wnext);
  gemm32_pre(wcur, xb0, l15, lq, acc);
#pragma unroll
  for (int mtl = 0; mtl < 2; ++mtl) {
    int m4 = (wv * 2 + mtl) * 16 + lq * 4;
    f32x4 sc = *(const f32x4*)(st + 1 * 256 + m4);
    f32x4 bi = *(const f32x4*)(st + 1 * 256 + 128 + m4);
#pragma unroll
    for (int nt = 0; nt < 2; ++nt) {
      int n_l = nt * 16 + l15;
      ushort4 v;
      v.x = f2b(fmaxf(acc[mtl][nt][0] * sc[0] + bi[0], 0.f));
      v.y = f2b(fmaxf(acc[mtl][nt][1] * sc[1] + bi[1], 0.f));
      v.z = f2b(fmaxf(acc[mtl][nt][2] * sc[2] + bi[2], 0.f));
      v.w = f2b(fmaxf(acc[mtl][nt][3] * sc[3] + bi[3], 0.f));
      *(ushort4*)(&xb1[n_l * 136 + m4]) = v;
    }
  }
  __syncthreads();

  // ---- stage 3: ext2 (K=128), xb1 -> xb0, + residual, store out0;
  //      prefetch W3 ----
#pragma unroll
  for (int mtl = 0; mtl < 2; ++mtl)
#pragma unroll
    for (int ks = 0; ks < 4; ++ks) wcur[mtl][ks] = wnext[mtl][ks];
  loadWfrag(W3, l15, lq, wv, wnext);
  gemm32_pre(wcur, xb1, l15, lq, acc);
#pragma unroll
  for (int mtl = 0; mtl < 2; ++mtl) {
    int m4 = (wv * 2 + mtl) * 16 + lq * 4;
    f32x4 sc = *(const f32x4*)(st + 2 * 256 + m4);
    f32x4 bi = *(const f32x4*)(st + 2 * 256 + 128 + m4);
#pragma unroll
    for (int nt = 0; nt < 2; ++nt) {
      int n_l = nt * 16 + l15;
      int n_g = n0 + n_l;
      ushort4 xp = *(const ushort4*)(&xb0[n_l * 136 + m4]);
      float v0 = fmaxf(acc[mtl][nt][0] * sc[0] + bi[0] + b2f(xp.x), 0.f);
      float v1 = fmaxf(acc[mtl][nt][1] * sc[1] + bi[1] + b2f(xp.y), 0.f);
      float v2 = fmaxf(acc[mtl][nt][2] * sc[2] + bi[2] + b2f(xp.z), 0.f);
      float v3 = fmaxf(acc[mtl][nt][3] * sc[3] + bi[3] + b2f(xp.w), 0.f);
      ushort4 v;
      v.x = f2b(v0); v.y = f2b(v1); v.z = f2b(v2); v.w = f2b(v3);
      *(ushort4*)(&xb0[n_l * 136 + m4]) = v;
      out[((size_t)(b * C_ + m4 + 0)) * N_ + n_g] = v0;
      out[((size_t)(b * C_ + m4 + 1)) * N_ + n_g] = v1;
      out[((size_t)(b * C_ + m4 + 2)) * N_ + n_g] = v2;
      out[((size_t)(b * C_ + m4 + 3)) * N_ + n_g] = v3;
    }
  }
  __syncthreads();

  // ---- stage 4: pred1 (K=128), xb0 -> xb1, store out1 ([B][N][128]) ----
  gemm32_pre(wnext, xb0, l15, lq, acc);
  {
    float* out1 = out + (size_t)B_ * C_ * N_;
#pragma unroll
    for (int mtl = 0; mtl < 2; ++mtl) {
      int m4 = (wv * 2 + mtl) * 16 + lq * 4;
      f32x4 sc = *(const f32x4*)(st + 3 * 256 + m4);
      f32x4 bi = *(const f32x4*)(st + 3 * 256 + 128 + m4);
#pragma unroll
      for (int nt = 0; nt < 2; ++nt) {
        int n_l = nt * 16 + l15;
        int n_g = n0 + n_l;
        float v0 = fmaxf(acc[mtl][nt][0] * sc[0] + bi[0], 0.f);
        float v1 = fmaxf(acc[mtl][nt][1] * sc[1] + bi[1], 0.f);
        float v2 = fmaxf(acc[mtl][nt][2] * sc[2] + bi[2], 0.f);
        float v3 = fmaxf(acc[mtl][nt][3] * sc[3] + bi[3], 0.f);
        ushort4 v;
        v.x = f2b(v0); v.y = f2b(v1); v.z = f2b(v2); v.w = f2b(v3);
        *(ushort4*)(&xb1[n_l * 136 + m4]) = v;
        float4 o4 = make_float4(v0, v1, v2, v3);
        *(float4*)(out1 + ((size_t)(b * N_ + n_g)) * 128 + m4) = o4;
      }
    }
  }
  __syncthreads();

  // ---- stage 5: pred2 (M=13 pad 16, K=128): waves 0,1 each do one nt ----
  if (wv < 2) {
    f32x4 a2 = (f32x4){0.f, 0.f, 0.f, 0.f};
#pragma unroll
    for (int ks = 0; ks < 4; ++ks) {
      int ko = ks * 32 + lq * 8;
      s16x8 b0 = *(const s16x8*)(&xb1[(wv * 16 + l15) * 136 + ko]);
      s16x8 a = *(const s16x8*)(Wp2 + (size_t)l15 * 128 + ko);
      a2 = MFMA16(a, b0, a2);
    }
    float* out2 = out + (size_t)B_ * C_ * N_ + (size_t)B_ * N_ * 128;
    f32x4 sc = *(const f32x4*)(st + 4 * 256 + lq * 4);
    f32x4 bi = *(const f32x4*)(st + 4 * 256 + 128 + lq * 4);
    int n_g = n0 + wv * 16 + l15;
#pragma unroll
    for (int r = 0; r < 4; ++r) {
      int m = lq * 4 + r;
      if (m < OC_) {
        out2[((size_t)(b * N_ + n_g)) * OC_ + m] =
            fmaxf(a2[r] * sc[r] + bi[r], 0.f);
      }
    }
  }
}

// ---------------------------------------------------------------------------
extern "C" void kernel_launch(void* const* d_in, const int* in_sizes, int n_in,
                              void* d_out, int out_size, void* d_ws, size_t ws_size,
                              hipStream_t stream) {
  const float* xyz1      = (const float*)d_in[0];
  const float* xyz2      = (const float*)d_in[1];
  const float* points1   = (const float*)d_in[2];
  const float* points2   = (const float*)d_in[3];
  const float* last_pred = (const float*)d_in[4];
  const float* fuse_W    = (const float*)d_in[5];
  const float* fuse_b    = (const float*)d_in[6];
  const float* fuse_bn   = (const float*)d_in[7];
  const float* ext1_W    = (const float*)d_in[8];
  const float* ext1_b    = (const float*)d_in[9];
  const float* ext1_bn   = (const float*)d_in[10];
  const float* ext2_W    = (const float*)d_in[11];
  const float* ext2_b    = (const float*)d_in[12];
  const float* ext2_bn   = (const float*)d_in[13];
  const float* pred1_W   = (const float*)d_in[14];
  const float* pred1_b   = (const float*)d_in[15];
  const float* pred1_bn  = (const float*)d_in[16];
  const float* pred2_W   = (const float*)d_in[17];
  const float* pred2_b   = (const float*)d_in[18];
  const float* pred2_bn  = (const float*)d_in[19];

  char* ws = (char*)d_ws;
  u16*   npT  = (u16*)(ws + 0);                // 2*16384*128*2 =  8,388,608
  u16*   p2t  = (u16*)(ws + 8388608);          // 2*4096*256*2  =  4,194,304
  u16*   cand = (u16*)(ws + 12582912);         // 2*16384*48*2  =  3,145,728
  u16*   Wf   = (u16*)(ws + 15728640);         // 128*416*2     =    106,496
  u16*   W1   = (u16*)(ws + 15835136);         // 128*128*2     =     32,768
  u16*   W2   = (u16*)(ws + 15867904);         //                     32,768
  u16*   W3   = (u16*)(ws + 15900672);         //                     32,768
  u16*   Wp2  = (u16*)(ws + 15933440);         // 16*128*2      =      4,096
  float* st   = (float*)(ws + 15937536);       // 5*256*4       =      5,120

  setup_scan_kernel<<<dim3(3648), dim3(256), 0, stream>>>(
      xyz1, xyz2, points1, points2,
      fuse_W, fuse_b, fuse_bn, ext1_W, ext1_b, ext1_bn, ext2_W, ext2_b, ext2_bn,
      pred1_W, pred1_b, pred1_bn, pred2_W, pred2_b, pred2_bn,
      cand, npT, p2t, Wf, W1, W2, W3, Wp2, st);

  mega_kernel<<<dim3(N_ / 32, B_), dim3(256), 0, stream>>>(
      xyz1, xyz2, cand, npT, p2t, last_pred,
      Wf, W1, W2, W3, Wp2, st, (float*)d_out);
}

// Round 10
// 203.775 us; speedup vs baseline: 1.2108x; 1.0084x over previous
//
#include <hip/hip_runtime.h>
#include <stdint.h>

#define B_   2
#define N_   16384
#define S_   4096
#define D2_  256
#define CIN_ 397
#define KP_  416      // Cin padded to 13*32 for MFMA K-slabs
#define C_   128
#define OC_  13
#define NCHUNK_ 16
#define CHS_ (S_ / NCHUNK_)       // 256 points per scan chunk
#define NCAND_ (NCHUNK_ * 3)      // 48 candidates per query
#define XBI_P 296                 // xbi LDS pitch in u16

typedef unsigned short u16;
typedef unsigned int u32;
typedef short s16x8 __attribute__((ext_vector_type(8)));
typedef float f32x4 __attribute__((ext_vector_type(4)));

#define MFMA16(a, b, c) __builtin_amdgcn_mfma_f32_16x16x32_bf16((a), (b), (c), 0, 0, 0)

__device__ __forceinline__ float b2f(u16 h) {
  union { unsigned int u; float f; } v; v.u = ((unsigned int)h) << 16; return v.f;
}
__device__ __forceinline__ u16 f2b(float f) {
  union { float f; unsigned int u; } v; v.f = f;
  unsigned int r = v.u + 0x7fffu + ((v.u >> 16) & 1u);
  return (u16)(r >> 16);
}

// 5-op branchless sorted-top3 insert on u32 keys
#define INS3U32(k0, k1, k2, key)            \
  do {                                      \
    u32 _t1 = max(k0, key);                 \
    u32 _t2 = max(k1, key);                 \
    k0 = min(k0, key);                      \
    k1 = min(k1, _t1);                      \
    k2 = min(k2, _t2);                      \
  } while (0)

// ---------------------------------------------------------------------------
// setup_scan: ONE launch. Blocks [0,2048): knn scan. [2048,3072): transpose
// points1 -> npT. [3072,3584): transpose points2 -> p2t. [3584,3648): prep.
// ---------------------------------------------------------------------------
__device__ __forceinline__ void transpose_body(
    const float* __restrict__ in, u16* __restrict__ out,
    int C, int S, int opitch, int b, int s0, int c0,
    float* __restrict__ tile, int tr, int tc4) {
  const float* ip = in + (size_t)b * C * S;
  u16* op = out + (size_t)b * S * opitch;
#pragma unroll
  for (int r = 0; r < 64; r += 16) {
    float4 v = *(const float4*)(ip + (size_t)(c0 + tr + r) * S + s0 + tc4);
    tile[(tr + r) * 65 + tc4 + 0] = v.x;
    tile[(tr + r) * 65 + tc4 + 1] = v.y;
    tile[(tr + r) * 65 + tc4 + 2] = v.z;
    tile[(tr + r) * 65 + tc4 + 3] = v.w;
  }
  __syncthreads();
#pragma unroll
  for (int r = 0; r < 64; r += 16) {
    ushort4 v;
    v.x = f2b(tile[(tc4 + 0) * 65 + tr + r]);
    v.y = f2b(tile[(tc4 + 1) * 65 + tr + r]);
    v.z = f2b(tile[(tc4 + 2) * 65 + tr + r]);
    v.w = f2b(tile[(tc4 + 3) * 65 + tr + r]);
    *(ushort4*)(op + (size_t)(s0 + tr + r) * opitch + c0 + tc4) = v;
  }
}

__global__ __launch_bounds__(256) void setup_scan_kernel(
    const float* __restrict__ xyz1, const float* __restrict__ xyz2,
    const float* __restrict__ points1, const float* __restrict__ points2,
    const float* __restrict__ fW, const float* __restrict__ fb,
    const float* __restrict__ fbn,
    const float* __restrict__ e1W, const float* __restrict__ e1b,
    const float* __restrict__ e1bn,
    const float* __restrict__ e2W, const float* __restrict__ e2b,
    const float* __restrict__ e2bn,
    const float* __restrict__ p1W, const float* __restrict__ p1b,
    const float* __restrict__ p1bn,
    const float* __restrict__ p2W, const float* __restrict__ p2b,
    const float* __restrict__ p2bn,
    u16* __restrict__ cand, u16* __restrict__ npT, u16* __restrict__ p2t,
    u16* __restrict__ Wf, u16* __restrict__ W1o,
    u16* __restrict__ W2o, u16* __restrict__ W3o,
    u16* __restrict__ Wp2, float* __restrict__ st) {
  __shared__ __align__(16) float smem[64 * 65];
  int id = blockIdx.x;
  int tid = threadIdx.x;

  if (id < 2048) {
    // ---- knn scan: branchless, two independent A/B top-3 sets ----
    float4* pts = (float4*)smem;
    int chunk = id & 15;
    int ny = (id >> 4) & 63;
    int b = id >> 10;
    int s0 = chunk * CHS_;
    const float* x2 = xyz2 + ((size_t)b * S_ + s0) * 3;
    {
      float xx = x2[tid * 3], yy = x2[tid * 3 + 1], zz = x2[tid * 3 + 2];
      pts[tid] = make_float4(xx, yy, zz, fmaf(xx, xx, fmaf(yy, yy, zz * zz)));
    }
    __syncthreads();
    int n = ny * 256 + tid;
    const float* x1 = xyz1 + ((size_t)b * N_ + n) * 3;
    float ax = x1[0], ay = x1[1], az = x1[2];
    float n1 = fmaf(ax, ax, fmaf(ay, ay, az * az));
    u32 a0k = 0xFFFFFFFFu, a1k = 0xFFFFFFFFu, a2k = 0xFFFFFFFFu;
    u32 b0k = 0xFFFFFFFFu, b1k = 0xFFFFFFFFu, b2k = 0xFFFFFFFFu;
#pragma unroll 4
    for (int s = 0; s < CHS_; s += 2) {
      float4 p = pts[s];
      float4 q = pts[s + 1];
      float dp = fmaf(ax, p.x, fmaf(ay, p.y, az * p.z));
      float dq = fmaf(ax, q.x, fmaf(ay, q.y, az * q.z));
      float da = fmaxf(fmaf(-2.f, dp, n1 + p.w), 0.f);
      float db = fmaxf(fmaf(-2.f, dq, n1 + q.w), 0.f);
      u32 ka = (__float_as_uint(da) & 0xFFFFFF00u) | (u32)s;
      u32 kb = (__float_as_uint(db) & 0xFFFFFF00u) | (u32)(s + 1);
      INS3U32(a0k, a1k, a2k, ka);
      INS3U32(b0k, b1k, b2k, kb);
    }
    INS3U32(a0k, a1k, a2k, b0k);
    INS3U32(a0k, a1k, a2k, b1k);
    INS3U32(a0k, a1k, a2k, b2k);
    u16* co = cand + ((size_t)(b * N_ + n)) * NCAND_ + chunk * 3;
    co[0] = (u16)((a0k & 0xFFu) + s0);
    co[1] = (u16)((a1k & 0xFFu) + s0);
    co[2] = (u16)((a2k & 0xFFu) + s0);
    return;
  }

  int tr = tid >> 4;
  int tc4 = (tid & 15) * 4;
  if (id < 3072) {
    int id2 = id - 2048;
    int sx = id2 & 255, sy = (id2 >> 8) & 1, b = id2 >> 9;
    transpose_body(points1, npT, 128, N_, 128, b, sx * 64, sy * 64, smem, tr, tc4);
    return;
  }
  if (id < 3584) {
    int id2 = id - 3072;
    int sx = id2 & 63, sy = (id2 >> 6) & 3, b = id2 >> 8;
    transpose_body(points2, p2t, 256, S_, 256, b, sx * 64, sy * 64, smem, tr, tc4);
    return;
  }
  int t = (id - 3584) * 256 + tid;
  int stride = 64 * 256;
  for (int i = t; i < 128 * KP_; i += stride) {
    int m = i / KP_, k = i - m * KP_;
    Wf[i] = (k < CIN_) ? f2b(fW[m * CIN_ + k]) : (u16)0;
  }
  for (int i = t; i < 128 * 128; i += stride) {
    W1o[i] = f2b(e1W[i]);
    W2o[i] = f2b(e2W[i]);
    W3o[i] = f2b(p1W[i]);
  }
  for (int i = t; i < 16 * 128; i += stride) {
    int m = i >> 7;
    Wp2[i] = (m < OC_) ? f2b(p2W[i]) : (u16)0;
  }
  for (int i = t; i < 5 * 128; i += stride) {
    int sg = i >> 7, c = i & 127;
    const float* bn; const float* bc; int Cc = 128;
    switch (sg) {
      case 0: bn = fbn;  bc = fb;  break;
      case 1: bn = e1bn; bc = e1b; break;
      case 2: bn = e2bn; bc = e2b; break;
      case 3: bn = p1bn; bc = p1b; break;
      default: bn = p2bn; bc = p2b; Cc = OC_; break;
    }
    float s = 0.f, tt = 0.f;
    if (c < Cc) {
      float g  = bn[0 * Cc + c], be = bn[1 * Cc + c];
      float mu = bn[2 * Cc + c], vv = bn[3 * Cc + c];
      float inv = 1.0f / sqrtf(vv + 1e-5f);
      s = g * inv;
      tt = (bc[c] - mu) * s + be;
    }
    st[sg * 256 + c] = s;
    st[sg * 256 + 128 + c] = tt;
  }
}

// ---------------------------------------------------------------------------
// f64 lexicographic (d, idx) top-3 insert -- matches stable top_k semantics
// ---------------------------------------------------------------------------
__device__ __forceinline__ void ins3(double d, int i,
                                     double& D0, double& D1, double& D2,
                                     int& I0, int& I1, int& I2) {
  if ((d < D2) || (d == D2 && i < I2)) {
    if ((d < D1) || (d == D1 && i < I1)) {
      D2 = D1; I2 = I1;
      if ((d < D0) || (d == D0 && i < I0)) { D1 = D0; I1 = I0; D0 = d; I0 = i; }
      else                                  { D1 = d; I1 = i; }
    } else { D2 = d; I2 = i; }
  }
}

// ---------------------------------------------------------------------------
// mega: 32-point tile, 1024 blocks, 4 blocks/CU. Explicit register batching
// of all scatter/gather loads (phase 0a cand coords; prologue p2t rows) to
// force memory-level parallelism -- one latency exposure, not eight.
// MFMA 16x16x32 bf16; A[m=lane&15][k=(lane>>4)*8+j]; D col=lane&15, row=q*4+r
// ---------------------------------------------------------------------------
__device__ __forceinline__ void gemm32(const u16* __restrict__ W, const u16* xb,
                                       int l15, int lq, int wv, f32x4 acc[2][2]) {
#pragma unroll
  for (int mtl = 0; mtl < 2; ++mtl) {
    acc[mtl][0] = (f32x4){0.f, 0.f, 0.f, 0.f};
    acc[mtl][1] = (f32x4){0.f, 0.f, 0.f, 0.f};
  }
#pragma unroll
  for (int ks = 0; ks < 4; ++ks) {
    int ko = ks * 32 + lq * 8;
    s16x8 b0 = *(const s16x8*)(xb + l15 * 136 + ko);
    s16x8 b1 = *(const s16x8*)(xb + (16 + l15) * 136 + ko);
#pragma unroll
    for (int mtl = 0; mtl < 2; ++mtl) {
      s16x8 a = *(const s16x8*)(W + (size_t)((wv * 2 + mtl) * 16 + l15) * 128 + ko);
      acc[mtl][0] = MFMA16(a, b0, acc[mtl][0]);
      acc[mtl][1] = MFMA16(a, b1, acc[mtl][1]);
    }
  }
}

__global__ __launch_bounds__(256, 4) void mega_kernel(
    const float* __restrict__ xyz1, const float* __restrict__ xyz2,
    const u16* __restrict__ cand,
    const u16* __restrict__ npT, const u16* __restrict__ p2t,
    const float* __restrict__ last_pred,
    const u16* __restrict__ Wf,
    const u16* __restrict__ W1, const u16* __restrict__ W2,
    const u16* __restrict__ W3, const u16* __restrict__ Wp2,
    const float* __restrict__ st, float* __restrict__ out) {
  __shared__ __align__(16) u16 xb0[32 * 136];
  __shared__ __align__(16) u16 xb1[32 * 136];
  __shared__ u16 xbi[32 * XBI_P];
  __shared__ float wL[32][3];
  __shared__ int   iL[32][3];
  int b = blockIdx.y;
  int n0 = blockIdx.x * 32;
  int tid = threadIdx.x;
  int wv = tid >> 6, lane = tid & 63;
  int l15 = lane & 15, lq = lane >> 4;
  f32x4 acc[2][2];

  // ---- phase 0a: f64 partial top-3 (8 threads/query, 6 cands each),
  //      candidate indices + coords batch-loaded into registers first ----
  {
#pragma clang fp contract(off)
    double* md = (double*)xb0;   // [32][24]
    int*    mi = (int*)xb1;      // [32][24]
    int qi = tid >> 3, part = tid & 7;
    int qg = b * N_ + n0 + qi;
    const u16* ci = cand + (size_t)qg * NCAND_ + part * 6;
    const float* x2b = xyz2 + (size_t)b * S_ * 3;
    int ii[6];
#pragma unroll
    for (int j = 0; j < 6; ++j) ii[j] = ci[j];
    float pcx[6], pcy[6], pcz[6];
#pragma unroll
    for (int j = 0; j < 6; ++j) {
      const float* p = x2b + (size_t)ii[j] * 3;
      pcx[j] = p[0]; pcy[j] = p[1]; pcz[j] = p[2];
    }
    const float* x1 = xyz1 + (size_t)qg * 3;
    double ax = x1[0], ay = x1[1], az = x1[2];
    double n1 = (ax * ax + ay * ay) + az * az;
    double D0 = 1e300, D1 = 1e300, D2v = 1e300;
    int I0 = 2147483647, I1 = 2147483647, I2 = 2147483647;
#pragma unroll
    for (int j = 0; j < 6; ++j) {
      double px = pcx[j], py = pcy[j], pz = pcz[j];
      double n2 = (px * px + py * py) + pz * pz;
      double dot = (ax * px + ay * py) + az * pz;
      double d = (n1 + n2) - 2.0 * dot;
      ins3(d, ii[j], D0, D1, D2v, I0, I1, I2);
    }
    md[qi * 24 + part * 3 + 0] = D0; mi[qi * 24 + part * 3 + 0] = I0;
    md[qi * 24 + part * 3 + 1] = D1; mi[qi * 24 + part * 3 + 1] = I1;
    md[qi * 24 + part * 3 + 2] = D2v; mi[qi * 24 + part * 3 + 2] = I2;
  }
  __syncthreads();

  // ---- phase 0b: exact combine + weights (one thread per query) ----
  if (tid < 32) {
#pragma clang fp contract(off)
    double* md = (double*)xb0;
    int*    mi = (int*)xb1;
    double D0 = 1e300, D1 = 1e300, D2v = 1e300;
    int I0 = 2147483647, I1 = 2147483647, I2 = 2147483647;
    for (int j = 0; j < 24; ++j) {
      ins3(md[tid * 24 + j], mi[tid * 24 + j], D0, D1, D2v, I0, I1, I2);
    }
    double r0 = 1.0 / (D0 + 1e-8);
    double r1 = 1.0 / (D1 + 1e-8);
    double r2 = 1.0 / (D2v + 1e-8);
    double sum = (r0 + r1) + r2;
    wL[tid][0] = (float)(r0 / sum);
    wL[tid][1] = (float)(r1 / sum);
    wL[tid][2] = (float)(r2 / sum);
    iL[tid][0] = I0; iL[tid][1] = I1; iL[tid][2] = I2;
  }
  __syncthreads();

  // ---- prologue: gather rows for all 8 points into registers FIRST
  //      (24 coalesced 512B row-loads in flight), then interpolate ----
  {
    const float* lpb = last_pred + (size_t)b * S_ * OC_;
    const u16* p2b = p2t + (size_t)b * S_ * D2_;
    ushort4 g0[8], g1[8], g2[8];
#pragma unroll
    for (int i = 0; i < 8; ++i) {
      int p = wv * 8 + i;
      int i0 = iL[p][0], i1 = iL[p][1], i2 = iL[p][2];
      g0[i] = *(const ushort4*)(p2b + (size_t)i0 * D2_ + lane * 4);
      g1[i] = *(const ushort4*)(p2b + (size_t)i1 * D2_ + lane * 4);
      g2[i] = *(const ushort4*)(p2b + (size_t)i2 * D2_ + lane * 4);
    }
#pragma unroll
    for (int i = 0; i < 8; ++i) {
      int p = wv * 8 + i;
      float w0 = wL[p][0], w1 = wL[p][1], w2 = wL[p][2];
      ushort4 v;
      v.x = f2b((w0 * b2f(g0[i].x) + w1 * b2f(g1[i].x)) + w2 * b2f(g2[i].x));
      v.y = f2b((w0 * b2f(g0[i].y) + w1 * b2f(g1[i].y)) + w2 * b2f(g2[i].y));
      v.z = f2b((w0 * b2f(g0[i].z) + w1 * b2f(g1[i].z)) + w2 * b2f(g2[i].z));
      v.w = f2b((w0 * b2f(g0[i].w) + w1 * b2f(g1[i].w)) + w2 * b2f(g2[i].w));
      *(ushort4*)(&xbi[p * XBI_P + lane * 4]) = v;
      if (lane < 32) {
        u16 pv = 0;
        if (lane < OC_) {
          int i0 = iL[p][0], i1 = iL[p][1], i2 = iL[p][2];
          pv = f2b((w0 * lpb[i0 * OC_ + lane] + w1 * lpb[i1 * OC_ + lane])
                   + w2 * lpb[i2 * OC_ + lane]);
        }
        xbi[p * XBI_P + 256 + lane] = pv;   // cols 256..287 (k=384..415)
      }
    }
  }
  __syncthreads();

  // ---- stage 1: fuse (K=416): k<128 from npT (global), k>=128 from xbi ----
#pragma unroll
  for (int mtl = 0; mtl < 2; ++mtl) {
    acc[mtl][0] = (f32x4){0.f, 0.f, 0.f, 0.f};
    acc[mtl][1] = (f32x4){0.f, 0.f, 0.f, 0.f};
  }
  {
    const u16* brow0 = npT + ((size_t)(b * N_ + n0 + l15)) * 128;
    const u16* brow1 = brow0 + (size_t)16 * 128;
#pragma unroll 1
    for (int ks = 0; ks < 4; ++ks) {
      int ko = ks * 32 + lq * 8;
      s16x8 bf0 = *(const s16x8*)(brow0 + ko);
      s16x8 bf1 = *(const s16x8*)(brow1 + ko);
#pragma unroll
      for (int mtl = 0; mtl < 2; ++mtl) {
        s16x8 a = *(const s16x8*)(Wf + (size_t)((wv * 2 + mtl) * 16 + l15) * KP_ + ko);
        acc[mtl][0] = MFMA16(a, bf0, acc[mtl][0]);
        acc[mtl][1] = MFMA16(a, bf1, acc[mtl][1]);
      }
    }
#pragma unroll 1
    for (int ks = 0; ks < 9; ++ks) {
      int kk = ks * 32 + lq * 8;
      s16x8 bf0 = *(const s16x8*)(&xbi[l15 * XBI_P + kk]);
      s16x8 bf1 = *(const s16x8*)(&xbi[(16 + l15) * XBI_P + kk]);
#pragma unroll
      for (int mtl = 0; mtl < 2; ++mtl) {
        s16x8 a = *(const s16x8*)(Wf + (size_t)((wv * 2 + mtl) * 16 + l15) * KP_ + 128 + kk);
        acc[mtl][0] = MFMA16(a, bf0, acc[mtl][0]);
        acc[mtl][1] = MFMA16(a, bf1, acc[mtl][1]);
      }
    }
  }
#pragma unroll
  for (int mtl = 0; mtl < 2; ++mtl) {
    int m4 = (wv * 2 + mtl) * 16 + lq * 4;
    f32x4 sc = *(const f32x4*)(st + 0 * 256 + m4);
    f32x4 bi = *(const f32x4*)(st + 0 * 256 + 128 + m4);
#pragma unroll
    for (int nt = 0; nt < 2; ++nt) {
      int n_l = nt * 16 + l15;
      ushort4 v;
      v.x = f2b(fmaxf(acc[mtl][nt][0] * sc[0] + bi[0], 0.f));
      v.y = f2b(fmaxf(acc[mtl][nt][1] * sc[1] + bi[1], 0.f));
      v.z = f2b(fmaxf(acc[mtl][nt][2] * sc[2] + bi[2], 0.f));
      v.w = f2b(fmaxf(acc[mtl][nt][3] * sc[3] + bi[3], 0.f));
      *(ushort4*)(&xb0[n_l * 136 + m4]) = v;
    }
  }
  __syncthreads();

  // ---- stage 2: ext1 (K=128), xb0 -> xb1 ----
  gemm32(W1, xb0, l15, lq, wv, acc);
#pragma unroll
  for (int mtl = 0; mtl < 2; ++mtl) {
    int m4 = (wv * 2 + mtl) * 16 + lq * 4;
    f32x4 sc = *(const f32x4*)(st + 1 * 256 + m4);
    f32x4 bi = *(const f32x4*)(st + 1 * 256 + 128 + m4);
#pragma unroll
    for (int nt = 0; nt < 2; ++nt) {
      int n_l = nt * 16 + l15;
      ushort4 v;
      v.x = f2b(fmaxf(acc[mtl][nt][0] * sc[0] + bi[0], 0.f));
      v.y = f2b(fmaxf(acc[mtl][nt][1] * sc[1] + bi[1], 0.f));
      v.z = f2b(fmaxf(acc[mtl][nt][2] * sc[2] + bi[2], 0.f));
      v.w = f2b(fmaxf(acc[mtl][nt][3] * sc[3] + bi[3], 0.f));
      *(ushort4*)(&xb1[n_l * 136 + m4]) = v;
    }
  }
  __syncthreads();

  // ---- stage 3: ext2 (K=128), xb1 -> xb0, + residual(xb0), store out0 ----
  gemm32(W2, xb1, l15, lq, wv, acc);
#pragma unroll
  for (int mtl = 0; mtl < 2; ++mtl) {
    int m4 = (wv * 2 + mtl) * 16 + lq * 4;
    f32x4 sc = *(const f32x4*)(st + 2 * 256 + m4);
    f32x4 bi = *(const f32x4*)(st + 2 * 256 + 128 + m4);
#pragma unroll
    for (int nt = 0; nt < 2; ++nt) {
      int n_l = nt * 16 + l15;
      int n_g = n0 + n_l;
      ushort4 xp = *(const ushort4*)(&xb0[n_l * 136 + m4]);
      float v0 = fmaxf(acc[mtl][nt][0] * sc[0] + bi[0] + b2f(xp.x), 0.f);
      float v1 = fmaxf(acc[mtl][nt][1] * sc[1] + bi[1] + b2f(xp.y), 0.f);
      float v2 = fmaxf(acc[mtl][nt][2] * sc[2] + bi[2] + b2f(xp.z), 0.f);
      float v3 = fmaxf(acc[mtl][nt][3] * sc[3] + bi[3] + b2f(xp.w), 0.f);
      ushort4 v;
      v.x = f2b(v0); v.y = f2b(v1); v.z = f2b(v2); v.w = f2b(v3);
      *(ushort4*)(&xb0[n_l * 136 + m4]) = v;
      out[((size_t)(b * C_ + m4 + 0)) * N_ + n_g] = v0;
      out[((size_t)(b * C_ + m4 + 1)) * N_ + n_g] = v1;
      out[((size_t)(b * C_ + m4 + 2)) * N_ + n_g] = v2;
      out[((size_t)(b * C_ + m4 + 3)) * N_ + n_g] = v3;
    }
  }
  __syncthreads();

  // ---- stage 4: pred1 (K=128), xb0 -> xb1, store out1 ([B][N][128]) ----
  gemm32(W3, xb0, l15, lq, wv, acc);
  {
    float* out1 = out + (size_t)B_ * C_ * N_;
#pragma unroll
    for (int mtl = 0; mtl < 2; ++mtl) {
      int m4 = (wv * 2 + mtl) * 16 + lq * 4;
      f32x4 sc = *(const f32x4*)(st + 3 * 256 + m4);
      f32x4 bi = *(const f32x4*)(st + 3 * 256 + 128 + m4);
#pragma unroll
      for (int nt = 0; nt < 2; ++nt) {
        int n_l = nt * 16 + l15;
        int n_g = n0 + n_l;
        float v0 = fmaxf(acc[mtl][nt][0] * sc[0] + bi[0], 0.f);
        float v1 = fmaxf(acc[mtl][nt][1] * sc[1] + bi[1], 0.f);
        float v2 = fmaxf(acc[mtl][nt][2] * sc[2] + bi[2], 0.f);
        float v3 = fmaxf(acc[mtl][nt][3] * sc[3] + bi[3], 0.f);
        ushort4 v;
        v.x = f2b(v0); v.y = f2b(v1); v.z = f2b(v2); v.w = f2b(v3);
        *(ushort4*)(&xb1[n_l * 136 + m4]) = v;
        float4 o4 = make_float4(v0, v1, v2, v3);
        *(float4*)(out1 + ((size_t)(b * N_ + n_g)) * 128 + m4) = o4;
      }
    }
  }
  __syncthreads();

  // ---- stage 5: pred2 (M=13 pad 16, K=128): waves 0,1 each do one nt ----
  if (wv < 2) {
    f32x4 a2 = (f32x4){0.f, 0.f, 0.f, 0.f};
#pragma unroll
    for (int ks = 0; ks < 4; ++ks) {
      int ko = ks * 32 + lq * 8;
      s16x8 b0 = *(const s16x8*)(&xb1[(wv * 16 + l15) * 136 + ko]);
      s16x8 a = *(const s16x8*)(Wp2 + (size_t)l15 * 128 + ko);
      a2 = MFMA16(a, b0, a2);
    }
    float* out2 = out + (size_t)B_ * C_ * N_ + (size_t)B_ * N_ * 128;
    f32x4 sc = *(const f32x4*)(st + 4 * 256 + lq * 4);
    f32x4 bi = *(const f32x4*)(st + 4 * 256 + 128 + lq * 4);
    int n_g = n0 + wv * 16 + l15;
#pragma unroll
    for (int r = 0; r < 4; ++r) {
      int m = lq * 4 + r;
      if (m < OC_) {
        out2[((size_t)(b * N_ + n_g)) * OC_ + m] =
            fmaxf(a2[r] * sc[r] + bi[r], 0.f);
      }
    }
  }
}

// ---------------------------------------------------------------------------
extern "C" void kernel_launch(void* const* d_in, const int* in_sizes, int n_in,
                              void* d_out, int out_size, void* d_ws, size_t ws_size,
                              hipStream_t stream) {
  const float* xyz1      = (const float*)d_in[0];
  const float* xyz2      = (const float*)d_in[1];
  const float* points1   = (const float*)d_in[2];
  const float* points2   = (const float*)d_in[3];
  const float* last_pred = (const float*)d_in[4];
  const float* fuse_W    = (const float*)d_in[5];
  const float* fuse_b    = (const float*)d_in[6];
  const float* fuse_bn   = (const float*)d_in[7];
  const float* ext1_W    = (const float*)d_in[8];
  const float* ext1_b    = (const float*)d_in[9];
  const float* ext1_bn   = (const float*)d_in[10];
  const float* ext2_W    = (const float*)d_in[11];
  const float* ext2_b    = (const float*)d_in[12];
  const float* ext2_bn   = (const float*)d_in[13];
  const float* pred1_W   = (const float*)d_in[14];
  const float* pred1_b   = (const float*)d_in[15];
  const float* pred1_bn  = (const float*)d_in[16];
  const float* pred2_W   = (const float*)d_in[17];
  const float* pred2_b   = (const float*)d_in[18];
  const float* pred2_bn  = (const float*)d_in[19];

  char* ws = (char*)d_ws;
  u16*   npT  = (u16*)(ws + 0);                // 2*16384*128*2 =  8,388,608
  u16*   p2t  = (u16*)(ws + 8388608);          // 2*4096*256*2  =  4,194,304
  u16*   cand = (u16*)(ws + 12582912);         // 2*16384*48*2  =  3,145,728
  u16*   Wf   = (u16*)(ws + 15728640);         // 128*416*2     =    106,496
  u16*   W1   = (u16*)(ws + 15835136);         // 128*128*2     =     32,768
  u16*   W2   = (u16*)(ws + 15867904);         //                     32,768
  u16*   W3   = (u16*)(ws + 15900672);         //                     32,768
  u16*   Wp2  = (u16*)(ws + 15933440);         // 16*128*2      =      4,096
  float* st   = (float*)(ws + 15937536);       // 5*256*4       =      5,120

  setup_scan_kernel<<<dim3(3648), dim3(256), 0, stream>>>(
      xyz1, xyz2, points1, points2,
      fuse_W, fuse_b, fuse_bn, ext1_W, ext1_b, ext1_bn, ext2_W, ext2_b, ext2_bn,
      pred1_W, pred1_b, pred1_bn, pred2_W, pred2_b, pred2_bn,
      cand, npT, p2t, Wf, W1, W2, W3, Wp2, st);

  mega_kernel<<<dim3(N_ / 32, B_), dim3(256), 0, stream>>>(
      xyz1, xyz2, cand, npT, p2t, last_pred,
      Wf, W1, W2, W3, Wp2, st, (float*)d_out);
}